// Round 7
// baseline (768.579 us; speedup 1.0000x reference)
//
#include <hip/hip_runtime.h>
#include <hip/hip_bf16.h>
#include <math.h>

#define N_NODES 100000
#define N_EDGES 3200000
#define F0 489
#define KPAD 512
#define BSHIFT2 7                 // 128-node buckets
#define NBUCK2 782                // ceil(100000/128)
#define BW_CHUNK 16384
#define SRC_MASK 0x1FFFF          // 17 bits for src (< 131072)

typedef __attribute__((ext_vector_type(8))) short short8;
typedef __attribute__((ext_vector_type(4))) float f32x4;
typedef unsigned short ushort_t;
typedef unsigned int uint_t;

__device__ __forceinline__ short f2bf(float v) {
    return __builtin_bit_cast(short, __float2bfloat16(v));
}
// bf16 pair in a dword -> two floats
__device__ __forceinline__ float pair_lo(uint_t v) {
    union { uint_t i; float f; } c; c.i = v << 16; return c.f;
}
__device__ __forceinline__ float pair_hi(uint_t v) {
    union { uint_t i; float f; } c; c.i = v & 0xffff0000u; return c.f;
}
__device__ __forceinline__ void add8(float* acc, uint4 d) {
    acc[0] += pair_lo(d.x); acc[1] += pair_hi(d.x);
    acc[2] += pair_lo(d.y); acc[3] += pair_hi(d.y);
    acc[4] += pair_lo(d.z); acc[5] += pair_hi(d.z);
    acc[6] += pair_lo(d.w); acc[7] += pair_hi(d.w);
}

// ---------------- zero int buffer ----------------
__global__ void k_zero(int* a, int n) {
    int i = blockIdx.x * blockDim.x + threadIdx.x;
    if (i < n) a[i] = 0;
}

// ---------------- bucket histogram (LDS-aggregated) ----------------
__global__ __launch_bounds__(256) void k_bcount(const int* __restrict__ dst,
                                                int* __restrict__ bcnt) {
    __shared__ int lc[NBUCK2];
    for (int b = threadIdx.x; b < NBUCK2; b += 256) lc[b] = 0;
    __syncthreads();
    for (int e = blockIdx.x * 256 + threadIdx.x; e < N_EDGES; e += gridDim.x * 256)
        atomicAdd(&lc[dst[e] >> BSHIFT2], 1);
    __syncthreads();
    for (int b = threadIdx.x; b < NBUCK2; b += 256)
        if (lc[b] > 0) atomicAdd(&bcnt[b], lc[b]);
}

// ---------------- 1024-wide scan of bucket counts -> bbase (exclusive) ----------------
__global__ __launch_bounds__(1024) void k_bscan(const int* __restrict__ bcnt,
                                                int* __restrict__ bbase) {
    __shared__ int tmp[1024];
    int i = threadIdx.x;
    int v = (i < NBUCK2) ? bcnt[i] : 0;
    tmp[i] = v;
    __syncthreads();
    for (int off = 1; off < 1024; off <<= 1) {
        int t = (i >= off) ? tmp[i - off] : 0;
        __syncthreads();
        tmp[i] += t;
        __syncthreads();
    }
    bbase[i] = tmp[i] - v;          // exclusive
    if (i == 1023) bbase[1024] = tmp[i];
}

// ---------------- bin edges into bucket-contiguous packed u32 stream ----------------
__global__ __launch_bounds__(256) void k_binwrite(const int* __restrict__ src,
                                                  const int* __restrict__ dst,
                                                  const int* __restrict__ bbase,
                                                  int* __restrict__ bcur,
                                                  uint_t* __restrict__ binned) {
    __shared__ int lcnt[NBUCK2];
    __shared__ int lpos[NBUCK2];
    for (int b = threadIdx.x; b < NBUCK2; b += 256) lcnt[b] = 0;
    __syncthreads();
    int e0 = blockIdx.x * BW_CHUNK;
    int e1 = e0 + BW_CHUNK; if (e1 > N_EDGES) e1 = N_EDGES;
    for (int e = e0 + threadIdx.x; e < e1; e += 256)
        atomicAdd(&lcnt[dst[e] >> BSHIFT2], 1);
    __syncthreads();
    for (int b = threadIdx.x; b < NBUCK2; b += 256) {
        int c = lcnt[b];
        lpos[b] = (c > 0) ? (bbase[b] + atomicAdd(&bcur[b], c)) : 0;
    }
    __syncthreads();
    for (int e = e0 + threadIdx.x; e < e1; e += 256) {
        int d = dst[e];
        int b = d >> BSHIFT2;
        int pos = atomicAdd(&lpos[b], 1);
        binned[pos] = (uint_t)src[e] | ((uint_t)(d & 127) << 17);
    }
}

// ---------------- per-bucket CSR build (one L2 window); emits rowptr, dinv ----------------
__global__ __launch_bounds__(256) void k_fill3(const int* __restrict__ bbase,
                                               const uint_t* __restrict__ binned,
                                               int* __restrict__ rowptr,
                                               float* __restrict__ dinv,
                                               int* __restrict__ csr) {
    __shared__ int cnt[128];
    __shared__ int tmp[128];
    __shared__ int pos[128];
    int b = blockIdx.x;
    int node0 = b << BSHIFT2;
    int lo = bbase[b], hi = bbase[b + 1];
    int t = threadIdx.x;
    if (t < 128) cnt[t] = 0;
    __syncthreads();
    for (int i = lo + t; i < hi; i += 256)
        atomicAdd(&cnt[binned[i] >> 17], 1);
    __syncthreads();
    if (t < 128) tmp[t] = cnt[t];
    __syncthreads();
    for (int o = 1; o < 128; o <<= 1) {
        int v = 0;
        if (t < 128 && t >= o) v = tmp[t - o];
        __syncthreads();
        if (t < 128) tmp[t] += v;
        __syncthreads();
    }
    if (t < 128) {
        int excl = tmp[t] - cnt[t];
        pos[t] = excl;
        int node = node0 + t;
        if (node < N_NODES) {
            rowptr[node] = lo + excl;
            dinv[node] = rsqrtf((float)cnt[t] + 1.0f);
        } else if (node == N_NODES) {
            rowptr[node] = lo + excl;
        }
    }
    __syncthreads();
    for (int i = lo + t; i < hi; i += 256) {
        uint_t v = binned[i];
        int dloc = v >> 17;
        int p = atomicAdd(&pos[dloc], 1);
        csr[lo + p] = (int)(v & SRC_MASK);
    }
}

// ---------------- W1 -> bf16, transposed+padded: Wt[n][k], n<64, k<512 ----------------
__global__ void k_cvtW(const float* __restrict__ W1, short* __restrict__ Wt) {
    int i = blockIdx.x * 256 + threadIdx.x;
    if (i < 64 * KPAD) {
        int n = i >> 9, k = i & (KPAD - 1);
        float v = (k < F0) ? W1[k * 64 + n] : 0.f;
        Wt[i] = f2bf(v);
    }
}

// ---------------- X -> bf16, padded to KPAD: Xb[row][512] (rows 1KB, 16B-aligned) ----------------
__global__ __launch_bounds__(256) void k_cvtX(const float* __restrict__ x,
                                              ushort_t* __restrict__ xb) {
    int row = blockIdx.x * 4 + (threadIdx.x >> 6);
    if (row >= N_NODES) return;
    int c8 = (threadIdx.x & 63) * 8;       // output col base, 0..504
    const float* xr = x + (size_t)row * F0 + c8;
    ushort_t tmp[8];
#pragma unroll
    for (int j = 0; j < 8; ++j) {
        float v = (c8 + j < F0) ? xr[j] : 0.f;
        tmp[j] = (ushort_t)f2bf(v);
    }
    *reinterpret_cast<uint4*>(xb + (size_t)row * KPAD + c8) =
        *reinterpret_cast<const uint4*>(tmp);
}

// ---------------- layer 1 MFMA GEMM v4: register-direct bf16, no LDS, no barriers ----------------
// block = 256 (4 waves); each wave owns 16 rows x 64 cols, full K (16 ks-steps).
// A-frag = one dwordx4 load from Xb; deep ILP, occupancy limited by VGPR only.
__global__ __launch_bounds__(256) void k_gemm1_mfma(const ushort_t* __restrict__ xb,
                                                    const short* __restrict__ Wt,
                                                    const float* __restrict__ dinv,
                                                    ushort_t* __restrict__ g1) {
    int wave = threadIdx.x >> 6;
    int lane = threadIdx.x & 63;
    int quad = lane >> 4;
    int m = lane & 15;
    int row0 = blockIdx.x * 64 + wave * 16;
    int row = row0 + m;
    int rowc = row < N_NODES ? row : N_NODES - 1;
    const short* xr = (const short*)xb + (size_t)rowc * KPAD + quad * 8;
    const short* wb = Wt + m * KPAD + quad * 8;

    f32x4 acc0 = {0.f, 0.f, 0.f, 0.f};
    f32x4 acc1 = {0.f, 0.f, 0.f, 0.f};
    f32x4 acc2 = {0.f, 0.f, 0.f, 0.f};
    f32x4 acc3 = {0.f, 0.f, 0.f, 0.f};

#pragma unroll
    for (int ks = 0; ks < 16; ++ks) {
        short8 af = *(const short8*)(xr + ks * 32);
        const short* wk = wb + ks * 32;
        short8 b0 = *(const short8*)(wk);
        short8 b1 = *(const short8*)(wk + 16 * KPAD);
        short8 b2 = *(const short8*)(wk + 32 * KPAD);
        short8 b3 = *(const short8*)(wk + 48 * KPAD);
        acc0 = __builtin_amdgcn_mfma_f32_16x16x32_bf16(af, b0, acc0, 0, 0, 0);
        acc1 = __builtin_amdgcn_mfma_f32_16x16x32_bf16(af, b1, acc1, 0, 0, 0);
        acc2 = __builtin_amdgcn_mfma_f32_16x16x32_bf16(af, b2, acc2, 0, 0, 0);
        acc3 = __builtin_amdgcn_mfma_f32_16x16x32_bf16(af, b3, acc3, 0, 0, 0);
    }

    // ---- epilogue: D layout col = lane&15, row = quad*4 + reg ----
#pragma unroll
    for (int r = 0; r < 4; r++) {
        int orow = row0 + quad * 4 + r;
        if (orow < N_NODES) {
            float s = dinv[orow];
            ushort_t* gr = g1 + (size_t)orow * 64 + m;
            gr[0]  = (ushort_t)f2bf(s * acc0[r]);
            gr[16] = (ushort_t)f2bf(s * acc1[r]);
            gr[32] = (ushort_t)f2bf(s * acc2[r]);
            gr[48] = (ushort_t)f2bf(s * acc3[r]);
        }
    }
}

// ---------------- gather64 v2: dwordx4 loads, 8 lanes/row, 16 edges per iter ----------------
__global__ __launch_bounds__(256) void k_gather64(const int* __restrict__ rowptr,
                                                  const int* __restrict__ csr,
                                                  const uint_t* __restrict__ g,
                                                  float* __restrict__ agg) {
    int node = blockIdx.x * 4 + (threadIdx.x >> 6);
    int lane = threadIdx.x & 63;
    int f4 = lane & 7;           // uint4 slot: features f4*8 .. f4*8+7
    int which = lane >> 3;       // 0..7
    int beg = rowptr[node], end = rowptr[node + 1];
    const uint4* g4 = reinterpret_cast<const uint4*>(g);   // row = 8 uint4
    float acc[8] = {0.f, 0.f, 0.f, 0.f, 0.f, 0.f, 0.f, 0.f};
    if (which == 0) {
        uint4 sv = g4[(size_t)node * 8 + f4];  // self loop
        add8(acc, sv);
    }
    for (int j0 = beg; j0 < end; j0 += 64) {
        int n = end - j0;
        if (n > 64) n = 64;
        int ev = csr[j0 + (lane < n ? lane : n - 1)];
        int i = 0;
        for (; i + 16 <= n; i += 16) {
            int s0 = __shfl(ev, i + which, 64);
            int s1 = __shfl(ev, i + 8 + which, 64);
            uint4 d0 = g4[(size_t)s0 * 8 + f4];
            uint4 d1 = g4[(size_t)s1 * 8 + f4];
            add8(acc, d0);
            add8(acc, d1);
        }
        for (; i < n; i += 8) {
            int idx = i + which;
            bool ok = idx < n;
            int s0 = __shfl(ev, ok ? idx : 0, 64);
            uint4 d0 = g4[(size_t)s0 * 8 + f4];
            if (ok) add8(acc, d0);
        }
    }
    // butterfly-reduce across the 8 which-groups (lanes differing in bits 3..5)
#pragma unroll
    for (int off = 8; off < 64; off <<= 1) {
#pragma unroll
        for (int k = 0; k < 8; k++) acc[k] += __shfl_xor(acc[k], off, 64);
    }
    if (which == 0) {
        float4 o0 = make_float4(acc[0], acc[1], acc[2], acc[3]);
        float4 o1 = make_float4(acc[4], acc[5], acc[6], acc[7]);
        float4* ap = reinterpret_cast<float4*>(agg + (size_t)node * 64 + f4 * 8);
        ap[0] = o0;
        ap[1] = o1;
    }
}

// ---------------- gather32 v2: dwordx4 loads, 4 lanes/row, 32 edges per iter ----------------
__global__ __launch_bounds__(256) void k_gather32(const int* __restrict__ rowptr,
                                                  const int* __restrict__ csr,
                                                  const uint_t* __restrict__ g,
                                                  float* __restrict__ agg) {
    int node = blockIdx.x * 4 + (threadIdx.x >> 6);
    int lane = threadIdx.x & 63;
    int f4 = lane & 3;           // uint4 slot: features f4*8 .. f4*8+7
    int which = lane >> 2;       // 0..15
    int beg = rowptr[node], end = rowptr[node + 1];
    const uint4* g4 = reinterpret_cast<const uint4*>(g);   // row = 4 uint4
    float acc[8] = {0.f, 0.f, 0.f, 0.f, 0.f, 0.f, 0.f, 0.f};
    if (which == 0) {
        uint4 sv = g4[(size_t)node * 4 + f4];  // self loop
        add8(acc, sv);
    }
    for (int j0 = beg; j0 < end; j0 += 64) {
        int n = end - j0;
        if (n > 64) n = 64;
        int ev = csr[j0 + (lane < n ? lane : n - 1)];
        int i = 0;
        for (; i + 32 <= n; i += 32) {
            int s0 = __shfl(ev, i + which, 64);
            int s1 = __shfl(ev, i + 16 + which, 64);
            uint4 d0 = g4[(size_t)s0 * 4 + f4];
            uint4 d1 = g4[(size_t)s1 * 4 + f4];
            add8(acc, d0);
            add8(acc, d1);
        }
        for (; i < n; i += 16) {
            int idx = i + which;
            bool ok = idx < n;
            int s0 = __shfl(ev, ok ? idx : 0, 64);
            uint4 d0 = g4[(size_t)s0 * 4 + f4];
            if (ok) add8(acc, d0);
        }
    }
    // butterfly-reduce across the 16 which-groups (lanes differing in bits 2..5)
#pragma unroll
    for (int off = 4; off < 64; off <<= 1) {
#pragma unroll
        for (int k = 0; k < 8; k++) acc[k] += __shfl_xor(acc[k], off, 64);
    }
    if (which == 0) {
        float4 o0 = make_float4(acc[0], acc[1], acc[2], acc[3]);
        float4 o1 = make_float4(acc[4], acc[5], acc[6], acc[7]);
        float4* ap = reinterpret_cast<float4*>(agg + (size_t)node * 32 + f4 * 8);
        ap[0] = o0;
        ap[1] = o1;
    }
}

// ---------------- gather, 2 fp32 features (one thread per node, float2) ----------------
__global__ __launch_bounds__(256) void k_gather2(const int* __restrict__ rowptr,
                                                 const int* __restrict__ csr,
                                                 const float* __restrict__ g,
                                                 float* __restrict__ agg) {
    int node = blockIdx.x * 256 + threadIdx.x;
    if (node >= N_NODES) return;
    int beg = rowptr[node], end = rowptr[node + 1];
    const float2* gp = reinterpret_cast<const float2*>(g);
    float2 acc = gp[node];
    for (int j = beg; j < end; j++) {
        float2 v = gp[csr[j]];
        acc.x += v.x;
        acc.y += v.y;
    }
    reinterpret_cast<float2*>(agg)[node] = acc;
}

// ---------------- layer 2: g2 = bf16( dinv .* (relu(dinv*agg1+b1) @ W2) ) ----------------
__global__ __launch_bounds__(256) void k_layer2(const float* __restrict__ agg1,
                                                const float* __restrict__ dinv,
                                                const float* __restrict__ b1,
                                                const float* __restrict__ W2,
                                                ushort_t* __restrict__ g2) {
    __shared__ float hs[32][65];
    __shared__ float Ws[64 * 32];
    for (int i = threadIdx.x; i < 64 * 32; i += 256) Ws[i] = W2[i];
    int row0 = blockIdx.x * 32;
    for (int i = threadIdx.x; i < 32 * 64; i += 256) {
        int r = i >> 6, f = i & 63;
        int row = row0 + r;
        float v = dinv[row] * agg1[(size_t)row * 64 + f] + b1[f];
        hs[r][f] = fmaxf(v, 0.f);
    }
    __syncthreads();
    int r = threadIdx.x >> 3;
    int j0 = (threadIdx.x & 7) * 4;
    int row = row0 + r;
    float a0 = 0.f, a1 = 0.f, a2 = 0.f, a3 = 0.f;
#pragma unroll 8
    for (int f = 0; f < 64; f++) {
        float h = hs[r][f];
        a0 += h * Ws[f * 32 + j0 + 0];
        a1 += h * Ws[f * 32 + j0 + 1];
        a2 += h * Ws[f * 32 + j0 + 2];
        a3 += h * Ws[f * 32 + j0 + 3];
    }
    float s = dinv[row];
    ushort_t* gr = g2 + (size_t)row * 32 + j0;
    gr[0] = (ushort_t)f2bf(s * a0);
    gr[1] = (ushort_t)f2bf(s * a1);
    gr[2] = (ushort_t)f2bf(s * a2);
    gr[3] = (ushort_t)f2bf(s * a3);
}

// ---------------- layer 3 ----------------
__global__ __launch_bounds__(256) void k_layer3(const float* __restrict__ agg2,
                                                const float* __restrict__ dinv,
                                                const float* __restrict__ b2,
                                                const float* __restrict__ W3,
                                                float* __restrict__ g3) {
    int row = blockIdx.x * blockDim.x + threadIdx.x;
    if (row >= N_NODES) return;
    float s = dinv[row];
    float t0 = 0.f, t1 = 0.f;
    const float4* ar = reinterpret_cast<const float4*>(agg2 + (size_t)row * 32);
#pragma unroll
    for (int q = 0; q < 8; q++) {
        float4 v = ar[q];
        float h;
        int f = q * 4;
        h = fmaxf(s * v.x + b2[f + 0], 0.f); t0 += h * W3[(f + 0) * 2]; t1 += h * W3[(f + 0) * 2 + 1];
        h = fmaxf(s * v.y + b2[f + 1], 0.f); t0 += h * W3[(f + 1) * 2]; t1 += h * W3[(f + 1) * 2 + 1];
        h = fmaxf(s * v.z + b2[f + 2], 0.f); t0 += h * W3[(f + 2) * 2]; t1 += h * W3[(f + 2) * 2 + 1];
        h = fmaxf(s * v.w + b2[f + 3], 0.f); t0 += h * W3[(f + 3) * 2]; t1 += h * W3[(f + 3) * 2 + 1];
    }
    float2 o = make_float2(s * t0, s * t1);
    *reinterpret_cast<float2*>(g3 + (size_t)row * 2) = o;
}

// ---------------- final log_softmax ----------------
__global__ void k_final(const float* __restrict__ agg3,
                        const float* __restrict__ dinv,
                        const float* __restrict__ b3,
                        float* __restrict__ out) {
    int row = blockIdx.x * blockDim.x + threadIdx.x;
    if (row >= N_NODES) return;
    float s = dinv[row];
    float2 a = *reinterpret_cast<const float2*>(agg3 + (size_t)row * 2);
    float z0 = s * a.x + b3[0];
    float z1 = s * a.y + b3[1];
    float m = fmaxf(z0, z1);
    float lse = m + logf(expf(z0 - m) + expf(z1 - m));
    out[(size_t)row * 2 + 0] = z0 - lse;
    out[(size_t)row * 2 + 1] = z1 - lse;
}

extern "C" void kernel_launch(void* const* d_in, const int* in_sizes, int n_in,
                              void* d_out, int out_size, void* d_ws, size_t ws_size,
                              hipStream_t stream) {
    const float* x  = (const float*)d_in[0];
    const int*   ei = (const int*)d_in[1];
    const float* W1 = (const float*)d_in[2];
    const float* b1 = (const float*)d_in[3];
    const float* W2 = (const float*)d_in[4];
    const float* b2 = (const float*)d_in[5];
    const float* W3 = (const float*)d_in[6];
    const float* b3 = (const float*)d_in[7];
    float* out = (float*)d_out;

    const int* src = ei;
    const int* dst = ei + N_EDGES;

    // ---- workspace layout (int elements) ----
    int* bcnt   = (int*)d_ws;                    // 1024
    int* bcur   = bcnt + 1024;                   // 1024  (zero bcnt+bcur = 2048)
    int* bbase  = bcur + 1024;                   // 1028
    int* rowptr = bbase + 1028;                  // 100004
    int* csr    = rowptr + 100004;               // 3200000
    float* dinv = (float*)(csr + 3200000);       // 100000
    short* Wt   = (short*)(dinv + 100000);       // 32768 shorts = 16384 ints
    uint_t* binned = (uint_t*)((int*)Wt + 16384);         // 3.2M u32 = 12.8 MB
    ushort_t* gbuf = (ushort_t*)(binned + N_EDGES);       // N*64 ushort = 12.8 MB
    float* aggF = (float*)(gbuf + (size_t)N_NODES * 64);  // N*64 fp32 = 25.6 MB
    ushort_t* xb = (ushort_t*)(aggF + (size_t)N_NODES * 64);  // N*512 bf16 = 102.4 MB

    ushort_t* gb1 = gbuf;
    ushort_t* gb2 = gbuf;
    float* g3     = (float*)gbuf;   // gb2 dead after gather32
    float* agg1 = aggF;
    float* agg2 = aggF;
    float* agg3 = aggF;

    const int TB = 256;
    int nb_nodes = (N_NODES + TB - 1) / TB;      // 391
    int nb_bw    = (N_EDGES + BW_CHUNK - 1) / BW_CHUNK;  // 196

    k_zero<<<8, TB, 0, stream>>>(bcnt, 2048);
    k_bcount<<<2048, TB, 0, stream>>>(dst, bcnt);
    k_bscan<<<1, 1024, 0, stream>>>(bcnt, bbase);
    k_binwrite<<<nb_bw, TB, 0, stream>>>(src, dst, bbase, bcur, binned);
    k_fill3<<<NBUCK2, TB, 0, stream>>>(bbase, binned, rowptr, dinv, csr);
    k_cvtW<<<(64 * KPAD + 255) / 256, 256, 0, stream>>>(W1, Wt);
    k_cvtX<<<(N_NODES + 3) / 4, TB, 0, stream>>>(x, xb);

    k_gemm1_mfma<<<(N_NODES + 63) / 64, TB, 0, stream>>>(xb, Wt, dinv, gb1);
    k_gather64<<<N_NODES / 4, TB, 0, stream>>>(rowptr, csr, (const uint_t*)gb1, agg1);

    k_layer2<<<N_NODES / 32, TB, 0, stream>>>(agg1, dinv, b1, W2, gb2);
    k_gather32<<<N_NODES / 4, TB, 0, stream>>>(rowptr, csr, (const uint_t*)gb2, agg2);

    k_layer3<<<nb_nodes, TB, 0, stream>>>(agg2, dinv, b2, W3, g3);
    k_gather2<<<nb_nodes, TB, 0, stream>>>(rowptr, csr, g3, agg3);

    k_final<<<nb_nodes, TB, 0, stream>>>(agg3, dinv, b3, out);
}

// Round 8
// 661.947 us; speedup vs baseline: 1.1611x; 1.1611x over previous
//
#include <hip/hip_runtime.h>
#include <hip/hip_bf16.h>
#include <math.h>

#define N_NODES 100000
#define N_EDGES 3200000
#define F0 489
#define KPAD 512
#define BSHIFT2 7                 // 128-node buckets
#define NBUCK2 782                // ceil(100000/128)
#define BW_CHUNK 16384
#define SRC_MASK 0x1FFFF          // 17 bits for src (< 131072)

typedef __attribute__((ext_vector_type(8))) short short8;
typedef __attribute__((ext_vector_type(4))) float f32x4;
typedef unsigned short ushort_t;
typedef unsigned int uint_t;

__device__ __forceinline__ short f2bf(float v) {
    return __builtin_bit_cast(short, __float2bfloat16(v));
}
// bf16 pair in a dword -> two floats
__device__ __forceinline__ float pair_lo(uint_t v) {
    union { uint_t i; float f; } c; c.i = v << 16; return c.f;
}
__device__ __forceinline__ float pair_hi(uint_t v) {
    union { uint_t i; float f; } c; c.i = v & 0xffff0000u; return c.f;
}
__device__ __forceinline__ void add8(float* acc, uint4 d) {
    acc[0] += pair_lo(d.x); acc[1] += pair_hi(d.x);
    acc[2] += pair_lo(d.y); acc[3] += pair_hi(d.y);
    acc[4] += pair_lo(d.z); acc[5] += pair_hi(d.z);
    acc[6] += pair_lo(d.w); acc[7] += pair_hi(d.w);
}

// ---------------- zero int buffer ----------------
__global__ void k_zero(int* a, int n) {
    int i = blockIdx.x * blockDim.x + threadIdx.x;
    if (i < n) a[i] = 0;
}

// ---------------- bucket histogram (LDS-aggregated) ----------------
__global__ __launch_bounds__(256) void k_bcount(const int* __restrict__ dst,
                                                int* __restrict__ bcnt) {
    __shared__ int lc[NBUCK2];
    for (int b = threadIdx.x; b < NBUCK2; b += 256) lc[b] = 0;
    __syncthreads();
    for (int e = blockIdx.x * 256 + threadIdx.x; e < N_EDGES; e += gridDim.x * 256)
        atomicAdd(&lc[dst[e] >> BSHIFT2], 1);
    __syncthreads();
    for (int b = threadIdx.x; b < NBUCK2; b += 256)
        if (lc[b] > 0) atomicAdd(&bcnt[b], lc[b]);
}

// ---------------- 1024-wide scan of bucket counts -> bbase (exclusive) ----------------
__global__ __launch_bounds__(1024) void k_bscan(const int* __restrict__ bcnt,
                                                int* __restrict__ bbase) {
    __shared__ int tmp[1024];
    int i = threadIdx.x;
    int v = (i < NBUCK2) ? bcnt[i] : 0;
    tmp[i] = v;
    __syncthreads();
    for (int off = 1; off < 1024; off <<= 1) {
        int t = (i >= off) ? tmp[i - off] : 0;
        __syncthreads();
        tmp[i] += t;
        __syncthreads();
    }
    bbase[i] = tmp[i] - v;          // exclusive
    if (i == 1023) bbase[1024] = tmp[i];
}

// ---------------- bin edges into bucket-contiguous packed u32 stream ----------------
__global__ __launch_bounds__(256) void k_binwrite(const int* __restrict__ src,
                                                  const int* __restrict__ dst,
                                                  const int* __restrict__ bbase,
                                                  int* __restrict__ bcur,
                                                  uint_t* __restrict__ binned) {
    __shared__ int lcnt[NBUCK2];
    __shared__ int lpos[NBUCK2];
    for (int b = threadIdx.x; b < NBUCK2; b += 256) lcnt[b] = 0;
    __syncthreads();
    int e0 = blockIdx.x * BW_CHUNK;
    int e1 = e0 + BW_CHUNK; if (e1 > N_EDGES) e1 = N_EDGES;
    for (int e = e0 + threadIdx.x; e < e1; e += 256)
        atomicAdd(&lcnt[dst[e] >> BSHIFT2], 1);
    __syncthreads();
    for (int b = threadIdx.x; b < NBUCK2; b += 256) {
        int c = lcnt[b];
        lpos[b] = (c > 0) ? (bbase[b] + atomicAdd(&bcur[b], c)) : 0;
    }
    __syncthreads();
    for (int e = e0 + threadIdx.x; e < e1; e += 256) {
        int d = dst[e];
        int b = d >> BSHIFT2;
        int pos = atomicAdd(&lpos[b], 1);
        binned[pos] = (uint_t)src[e] | ((uint_t)(d & 127) << 17);
    }
}

// ---------------- per-bucket CSR build (one L2 window); emits rowptr, dinv ----------------
__global__ __launch_bounds__(256) void k_fill3(const int* __restrict__ bbase,
                                               const uint_t* __restrict__ binned,
                                               int* __restrict__ rowptr,
                                               float* __restrict__ dinv,
                                               int* __restrict__ csr) {
    __shared__ int cnt[128];
    __shared__ int tmp[128];
    __shared__ int pos[128];
    int b = blockIdx.x;
    int node0 = b << BSHIFT2;
    int lo = bbase[b], hi = bbase[b + 1];
    int t = threadIdx.x;
    if (t < 128) cnt[t] = 0;
    __syncthreads();
    for (int i = lo + t; i < hi; i += 256)
        atomicAdd(&cnt[binned[i] >> 17], 1);
    __syncthreads();
    if (t < 128) tmp[t] = cnt[t];
    __syncthreads();
    for (int o = 1; o < 128; o <<= 1) {
        int v = 0;
        if (t < 128 && t >= o) v = tmp[t - o];
        __syncthreads();
        if (t < 128) tmp[t] += v;
        __syncthreads();
    }
    if (t < 128) {
        int excl = tmp[t] - cnt[t];
        pos[t] = excl;
        int node = node0 + t;
        if (node < N_NODES) {
            rowptr[node] = lo + excl;
            dinv[node] = rsqrtf((float)cnt[t] + 1.0f);
        } else if (node == N_NODES) {
            rowptr[node] = lo + excl;
        }
    }
    __syncthreads();
    for (int i = lo + t; i < hi; i += 256) {
        uint_t v = binned[i];
        int dloc = v >> 17;
        int p = atomicAdd(&pos[dloc], 1);
        csr[lo + p] = (int)(v & SRC_MASK);
    }
}

// ---------------- W1 -> bf16, transposed+padded: Wt[n][k], n<64, k<512 ----------------
__global__ void k_cvtW(const float* __restrict__ W1, short* __restrict__ Wt) {
    int i = blockIdx.x * 256 + threadIdx.x;
    if (i < 64 * KPAD) {
        int n = i >> 9, k = i & (KPAD - 1);
        float v = (k < F0) ? W1[k * 64 + n] : 0.f;
        Wt[i] = f2bf(v);
    }
}

// ---------------- layer 1 MFMA GEMM (R4 proven): LDS-staged via global_load_lds ----------------
// block = 256 (4 waves); 64 rows/block, each wave owns 16 rows x all 64 cols, full K.
// K processed in 8 chunks of 64 floats staged into LDS (async DMA), 2-barrier loop.
__global__ __launch_bounds__(256) void k_gemm1_mfma(const float* __restrict__ x,
                                                    const short* __restrict__ Wt,
                                                    const float* __restrict__ dinv,
                                                    ushort_t* __restrict__ g1) {
    __shared__ float xs[64][68];         // 17.4 KB; +4 pad -> 2-way LDS conflict (free)
    int wave = threadIdx.x >> 6;
    int lane = threadIdx.x & 63;
    int quad = lane >> 4;
    int m = lane & 15;
    int row0 = blockIdx.x * 64;
    int wrow0 = wave * 16;

    f32x4 acc0 = {0.f, 0.f, 0.f, 0.f};
    f32x4 acc1 = {0.f, 0.f, 0.f, 0.f};
    f32x4 acc2 = {0.f, 0.f, 0.f, 0.f};
    f32x4 acc3 = {0.f, 0.f, 0.f, 0.f};

    const short* wb = Wt + m * KPAD + quad * 8;   // col-block 0 base
    const size_t XMAX = (size_t)N_NODES * F0 - 1;

    for (int chunk = 0; chunk < 8; ++chunk) {
        int kc = chunk * 64;
        __syncthreads();                 // previous chunk fully consumed
#pragma unroll
        for (int i = 0; i < 16; ++i) {
            int grow = row0 + wrow0 + i;
            int rowc = grow < N_NODES ? grow : N_NODES - 1;
            size_t gidx = (size_t)rowc * F0 + kc + lane;
            if (chunk == 7 && gidx > XMAX) gidx = XMAX;   // tail-of-row clamp
            __builtin_amdgcn_global_load_lds(
                (const __attribute__((address_space(1))) uint_t*)(x + gidx),
                (__attribute__((address_space(3))) uint_t*)&xs[wrow0 + i][0],
                4, 0, 0);
        }
        __syncthreads();                 // staging drained

        const float* lrow = &xs[wrow0 + m][0];
        if (chunk < 7) {
#pragma unroll
            for (int ksl = 0; ksl < 2; ++ksl) {
                const float* lr = lrow + ksl * 32 + quad * 8;
                f32x4 a0 = *(const f32x4*)(lr);
                f32x4 a1 = *(const f32x4*)(lr + 4);
                short8 af;
#pragma unroll
                for (int j = 0; j < 4; ++j) { af[j] = f2bf(a0[j]); af[4 + j] = f2bf(a1[j]); }
                const short* wk = wb + (chunk * 2 + ksl) * 32;
                short8 b0 = *(const short8*)(wk);
                short8 b1 = *(const short8*)(wk + 16 * KPAD);
                short8 b2 = *(const short8*)(wk + 32 * KPAD);
                short8 b3 = *(const short8*)(wk + 48 * KPAD);
                acc0 = __builtin_amdgcn_mfma_f32_16x16x32_bf16(af, b0, acc0, 0, 0, 0);
                acc1 = __builtin_amdgcn_mfma_f32_16x16x32_bf16(af, b1, acc1, 0, 0, 0);
                acc2 = __builtin_amdgcn_mfma_f32_16x16x32_bf16(af, b2, acc2, 0, 0, 0);
                acc3 = __builtin_amdgcn_mfma_f32_16x16x32_bf16(af, b3, acc3, 0, 0, 0);
            }
        } else {
            {   // ks_global = 14, k = 448..479, all valid
                const float* lr = lrow + quad * 8;
                f32x4 a0 = *(const f32x4*)(lr);
                f32x4 a1 = *(const f32x4*)(lr + 4);
                short8 af;
#pragma unroll
                for (int j = 0; j < 4; ++j) { af[j] = f2bf(a0[j]); af[4 + j] = f2bf(a1[j]); }
                const short* wk = wb + 14 * 32;
                short8 b0 = *(const short8*)(wk);
                short8 b1 = *(const short8*)(wk + 16 * KPAD);
                short8 b2 = *(const short8*)(wk + 32 * KPAD);
                short8 b3 = *(const short8*)(wk + 48 * KPAD);
                acc0 = __builtin_amdgcn_mfma_f32_16x16x32_bf16(af, b0, acc0, 0, 0, 0);
                acc1 = __builtin_amdgcn_mfma_f32_16x16x32_bf16(af, b1, acc1, 0, 0, 0);
                acc2 = __builtin_amdgcn_mfma_f32_16x16x32_bf16(af, b2, acc2, 0, 0, 0);
                acc3 = __builtin_amdgcn_mfma_f32_16x16x32_bf16(af, b3, acc3, 0, 0, 0);
            }
            {   // ks_global = 15, k = 480..511, valid only k < 489
                int kb = 480 + quad * 8;
                const float* lr = lrow + 32 + quad * 8;
                short8 af;
#pragma unroll
                for (int j = 0; j < 8; ++j)
                    af[j] = (kb + j < F0) ? f2bf(lr[j]) : (short)0;
                const short* wk = wb + 15 * 32;
                short8 b0 = *(const short8*)(wk);
                short8 b1 = *(const short8*)(wk + 16 * KPAD);
                short8 b2 = *(const short8*)(wk + 32 * KPAD);
                short8 b3 = *(const short8*)(wk + 48 * KPAD);
                acc0 = __builtin_amdgcn_mfma_f32_16x16x32_bf16(af, b0, acc0, 0, 0, 0);
                acc1 = __builtin_amdgcn_mfma_f32_16x16x32_bf16(af, b1, acc1, 0, 0, 0);
                acc2 = __builtin_amdgcn_mfma_f32_16x16x32_bf16(af, b2, acc2, 0, 0, 0);
                acc3 = __builtin_amdgcn_mfma_f32_16x16x32_bf16(af, b3, acc3, 0, 0, 0);
            }
        }
    }

    // ---- epilogue: D layout col = lane&15, row = quad*4 + reg ----
#pragma unroll
    for (int r = 0; r < 4; r++) {
        int orow = row0 + wrow0 + quad * 4 + r;
        if (orow < N_NODES) {
            float s = dinv[orow];
            ushort_t* gr = g1 + (size_t)orow * 64 + m;
            gr[0]  = (ushort_t)f2bf(s * acc0[r]);
            gr[16] = (ushort_t)f2bf(s * acc1[r]);
            gr[32] = (ushort_t)f2bf(s * acc2[r]);
            gr[48] = (ushort_t)f2bf(s * acc3[r]);
        }
    }
}

// ---------------- gather64 v3: 2 nodes/wave, 8 lanes/row, 4 edges in flight/node ----------------
__global__ __launch_bounds__(256) void k_gather64(const int* __restrict__ rowptr,
                                                  const int* __restrict__ csr,
                                                  const uint_t* __restrict__ g,
                                                  float* __restrict__ agg) {
    int node = blockIdx.x * 8 + (threadIdx.x >> 5);
    int lane = threadIdx.x & 63;
    int l2 = lane & 31;
    int f4 = l2 & 7;             // uint4 slot: features f4*8 .. f4*8+7
    int which = l2 >> 3;         // 0..3
    int g32 = (lane >> 5) * 32;  // shfl base for this half-wave
    int beg = rowptr[node], end = rowptr[node + 1];
    const uint4* g4 = reinterpret_cast<const uint4*>(g);   // row = 8 uint4
    float acc[8] = {0.f, 0.f, 0.f, 0.f, 0.f, 0.f, 0.f, 0.f};
    if (which == 0) {
        uint4 sv = g4[(size_t)node * 8 + f4];  // self loop
        add8(acc, sv);
    }
    for (int j0 = beg; j0 < end; j0 += 32) {
        int n = end - j0;
        if (n > 32) n = 32;
        int ev = csr[j0 + (l2 < n ? l2 : n - 1)];
        int i = 0;
        for (; i + 8 <= n; i += 8) {
            int s0 = __shfl(ev, g32 + i + which, 64);
            int s1 = __shfl(ev, g32 + i + 4 + which, 64);
            uint4 d0 = g4[(size_t)s0 * 8 + f4];
            uint4 d1 = g4[(size_t)s1 * 8 + f4];
            add8(acc, d0);
            add8(acc, d1);
        }
        for (; i < n; i += 4) {
            int idx = i + which;
            bool ok = idx < n;
            int s0 = __shfl(ev, g32 + (ok ? idx : 0), 64);
            uint4 d0 = g4[(size_t)s0 * 8 + f4];
            if (ok) add8(acc, d0);
        }
    }
    // reduce across the 4 which-groups (bits 3..4 of l2; stays within half-wave)
#pragma unroll
    for (int off = 8; off < 32; off <<= 1) {
#pragma unroll
        for (int k = 0; k < 8; k++) acc[k] += __shfl_xor(acc[k], off, 64);
    }
    if (which == 0) {
        float4 o0 = make_float4(acc[0], acc[1], acc[2], acc[3]);
        float4 o1 = make_float4(acc[4], acc[5], acc[6], acc[7]);
        float4* ap = reinterpret_cast<float4*>(agg + (size_t)node * 64 + f4 * 8);
        ap[0] = o0;
        ap[1] = o1;
    }
}

// ---------------- gather32 v3: 4 nodes/wave, 4 lanes/row, 4 edges in flight/node ----------------
__global__ __launch_bounds__(256) void k_gather32(const int* __restrict__ rowptr,
                                                  const int* __restrict__ csr,
                                                  const uint_t* __restrict__ g,
                                                  float* __restrict__ agg) {
    int node = blockIdx.x * 16 + (threadIdx.x >> 4);
    int lane = threadIdx.x & 63;
    int l2 = lane & 15;
    int f4 = l2 & 3;             // uint4 slot: features f4*8 .. f4*8+7
    int which = l2 >> 2;         // 0..3
    int g16 = (lane >> 4) * 16;  // shfl base for this quarter-wave
    int beg = rowptr[node], end = rowptr[node + 1];
    const uint4* g4 = reinterpret_cast<const uint4*>(g);   // row = 4 uint4
    float acc[8] = {0.f, 0.f, 0.f, 0.f, 0.f, 0.f, 0.f, 0.f};
    if (which == 0) {
        uint4 sv = g4[(size_t)node * 4 + f4];  // self loop
        add8(acc, sv);
    }
    for (int j0 = beg; j0 < end; j0 += 16) {
        int n = end - j0;
        if (n > 16) n = 16;
        int ev = csr[j0 + (l2 < n ? l2 : n - 1)];
        int i = 0;
        for (; i + 8 <= n; i += 8) {
            int s0 = __shfl(ev, g16 + i + which, 64);
            int s1 = __shfl(ev, g16 + i + 4 + which, 64);
            uint4 d0 = g4[(size_t)s0 * 4 + f4];
            uint4 d1 = g4[(size_t)s1 * 4 + f4];
            add8(acc, d0);
            add8(acc, d1);
        }
        for (; i < n; i += 4) {
            int idx = i + which;
            bool ok = idx < n;
            int s0 = __shfl(ev, g16 + (ok ? idx : 0), 64);
            uint4 d0 = g4[(size_t)s0 * 4 + f4];
            if (ok) add8(acc, d0);
        }
    }
    // reduce across the 4 which-groups (bits 2..3 of l2; stays within quarter-wave)
#pragma unroll
    for (int off = 4; off < 16; off <<= 1) {
#pragma unroll
        for (int k = 0; k < 8; k++) acc[k] += __shfl_xor(acc[k], off, 64);
    }
    if (which == 0) {
        float4 o0 = make_float4(acc[0], acc[1], acc[2], acc[3]);
        float4 o1 = make_float4(acc[4], acc[5], acc[6], acc[7]);
        float4* ap = reinterpret_cast<float4*>(agg + (size_t)node * 32 + f4 * 8);
        ap[0] = o0;
        ap[1] = o1;
    }
}

// ---------------- gather2 v2: 8 lanes per node, 8 edge-loads in flight ----------------
__global__ __launch_bounds__(256) void k_gather2(const int* __restrict__ rowptr,
                                                 const int* __restrict__ csr,
                                                 const float* __restrict__ g,
                                                 float* __restrict__ agg) {
    int node = blockIdx.x * 32 + (threadIdx.x >> 3);
    int l8 = threadIdx.x & 7;
    int beg = rowptr[node], end = rowptr[node + 1];
    const float2* gp = reinterpret_cast<const float2*>(g);
    float ax = 0.f, ay = 0.f;
    if (l8 == 0) {
        float2 sv = gp[node];
        ax = sv.x; ay = sv.y;
    }
    for (int j = beg + l8; j < end; j += 8) {
        float2 v = gp[csr[j]];
        ax += v.x;
        ay += v.y;
    }
#pragma unroll
    for (int off = 1; off < 8; off <<= 1) {
        ax += __shfl_xor(ax, off, 64);
        ay += __shfl_xor(ay, off, 64);
    }
    if (l8 == 0) {
        reinterpret_cast<float2*>(agg)[node] = make_float2(ax, ay);
    }
}

// ---------------- layer 2: g2 = bf16( dinv .* (relu(dinv*agg1+b1) @ W2) ) ----------------
__global__ __launch_bounds__(256) void k_layer2(const float* __restrict__ agg1,
                                                const float* __restrict__ dinv,
                                                const float* __restrict__ b1,
                                                const float* __restrict__ W2,
                                                ushort_t* __restrict__ g2) {
    __shared__ float hs[32][65];
    __shared__ float Ws[64 * 32];
    for (int i = threadIdx.x; i < 64 * 32; i += 256) Ws[i] = W2[i];
    int row0 = blockIdx.x * 32;
    for (int i = threadIdx.x; i < 32 * 64; i += 256) {
        int r = i >> 6, f = i & 63;
        int row = row0 + r;
        float v = dinv[row] * agg1[(size_t)row * 64 + f] + b1[f];
        hs[r][f] = fmaxf(v, 0.f);
    }
    __syncthreads();
    int r = threadIdx.x >> 3;
    int j0 = (threadIdx.x & 7) * 4;
    int row = row0 + r;
    float a0 = 0.f, a1 = 0.f, a2 = 0.f, a3 = 0.f;
#pragma unroll 8
    for (int f = 0; f < 64; f++) {
        float h = hs[r][f];
        a0 += h * Ws[f * 32 + j0 + 0];
        a1 += h * Ws[f * 32 + j0 + 1];
        a2 += h * Ws[f * 32 + j0 + 2];
        a3 += h * Ws[f * 32 + j0 + 3];
    }
    float s = dinv[row];
    ushort_t* gr = g2 + (size_t)row * 32 + j0;
    gr[0] = (ushort_t)f2bf(s * a0);
    gr[1] = (ushort_t)f2bf(s * a1);
    gr[2] = (ushort_t)f2bf(s * a2);
    gr[3] = (ushort_t)f2bf(s * a3);
}

// ---------------- layer 3 ----------------
__global__ __launch_bounds__(256) void k_layer3(const float* __restrict__ agg2,
                                                const float* __restrict__ dinv,
                                                const float* __restrict__ b2,
                                                const float* __restrict__ W3,
                                                float* __restrict__ g3) {
    int row = blockIdx.x * blockDim.x + threadIdx.x;
    if (row >= N_NODES) return;
    float s = dinv[row];
    float t0 = 0.f, t1 = 0.f;
    const float4* ar = reinterpret_cast<const float4*>(agg2 + (size_t)row * 32);
#pragma unroll
    for (int q = 0; q < 8; q++) {
        float4 v = ar[q];
        float h;
        int f = q * 4;
        h = fmaxf(s * v.x + b2[f + 0], 0.f); t0 += h * W3[(f + 0) * 2]; t1 += h * W3[(f + 0) * 2 + 1];
        h = fmaxf(s * v.y + b2[f + 1], 0.f); t0 += h * W3[(f + 1) * 2]; t1 += h * W3[(f + 1) * 2 + 1];
        h = fmaxf(s * v.z + b2[f + 2], 0.f); t0 += h * W3[(f + 2) * 2]; t1 += h * W3[(f + 2) * 2 + 1];
        h = fmaxf(s * v.w + b2[f + 3], 0.f); t0 += h * W3[(f + 3) * 2]; t1 += h * W3[(f + 3) * 2 + 1];
    }
    float2 o = make_float2(s * t0, s * t1);
    *reinterpret_cast<float2*>(g3 + (size_t)row * 2) = o;
}

// ---------------- final log_softmax ----------------
__global__ void k_final(const float* __restrict__ agg3,
                        const float* __restrict__ dinv,
                        const float* __restrict__ b3,
                        float* __restrict__ out) {
    int row = blockIdx.x * blockDim.x + threadIdx.x;
    if (row >= N_NODES) return;
    float s = dinv[row];
    float2 a = *reinterpret_cast<const float2*>(agg3 + (size_t)row * 2);
    float z0 = s * a.x + b3[0];
    float z1 = s * a.y + b3[1];
    float m = fmaxf(z0, z1);
    float lse = m + logf(expf(z0 - m) + expf(z1 - m));
    out[(size_t)row * 2 + 0] = z0 - lse;
    out[(size_t)row * 2 + 1] = z1 - lse;
}

extern "C" void kernel_launch(void* const* d_in, const int* in_sizes, int n_in,
                              void* d_out, int out_size, void* d_ws, size_t ws_size,
                              hipStream_t stream) {
    const float* x  = (const float*)d_in[0];
    const int*   ei = (const int*)d_in[1];
    const float* W1 = (const float*)d_in[2];
    const float* b1 = (const float*)d_in[3];
    const float* W2 = (const float*)d_in[4];
    const float* b2 = (const float*)d_in[5];
    const float* W3 = (const float*)d_in[6];
    const float* b3 = (const float*)d_in[7];
    float* out = (float*)d_out;

    const int* src = ei;
    const int* dst = ei + N_EDGES;

    // ---- workspace layout (int elements) ----
    int* bcnt   = (int*)d_ws;                    // 1024
    int* bcur   = bcnt + 1024;                   // 1024  (zero bcnt+bcur = 2048)
    int* bbase  = bcur + 1024;                   // 1028
    int* rowptr = bbase + 1028;                  // 100004
    int* csr    = rowptr + 100004;               // 3200000
    float* dinv = (float*)(csr + 3200000);       // 100000
    short* Wt   = (short*)(dinv + 100000);       // 32768 shorts = 16384 ints
    uint_t* binned = (uint_t*)((int*)Wt + 16384);         // 3.2M u32 = 12.8 MB
    ushort_t* gbuf = (ushort_t*)(binned + N_EDGES);       // N*64 ushort = 12.8 MB
    float* aggF = (float*)(gbuf + (size_t)N_NODES * 64);  // N*64 fp32 = 25.6 MB

    ushort_t* gb1 = gbuf;
    ushort_t* gb2 = gbuf;
    float* g3     = (float*)gbuf;   // gb2 dead after gather32
    float* agg1 = aggF;
    float* agg2 = aggF;
    float* agg3 = aggF;

    const int TB = 256;
    int nb_nodes = (N_NODES + TB - 1) / TB;      // 391
    int nb_bw    = (N_EDGES + BW_CHUNK - 1) / BW_CHUNK;  // 196

    k_zero<<<8, TB, 0, stream>>>(bcnt, 2048);
    k_bcount<<<2048, TB, 0, stream>>>(dst, bcnt);
    k_bscan<<<1, 1024, 0, stream>>>(bcnt, bbase);
    k_binwrite<<<nb_bw, TB, 0, stream>>>(src, dst, bbase, bcur, binned);
    k_fill3<<<NBUCK2, TB, 0, stream>>>(bbase, binned, rowptr, dinv, csr);
    k_cvtW<<<(64 * KPAD + 255) / 256, 256, 0, stream>>>(W1, Wt);

    k_gemm1_mfma<<<(N_NODES + 63) / 64, TB, 0, stream>>>(x, Wt, dinv, gb1);
    k_gather64<<<N_NODES / 8, TB, 0, stream>>>(rowptr, csr, (const uint_t*)gb1, agg1);

    k_layer2<<<N_NODES / 32, TB, 0, stream>>>(agg1, dinv, b1, W2, gb2);
    k_gather32<<<N_NODES / 16, TB, 0, stream>>>(rowptr, csr, (const uint_t*)gb2, agg2);

    k_layer3<<<nb_nodes, TB, 0, stream>>>(agg2, dinv, b2, W3, g3);
    k_gather2<<<N_NODES / 32, TB, 0, stream>>>(rowptr, csr, g3, agg3);

    k_final<<<nb_nodes, TB, 0, stream>>>(agg3, dinv, b3, out);
}

// Round 9
// 656.159 us; speedup vs baseline: 1.1713x; 1.0088x over previous
//
#include <hip/hip_runtime.h>
#include <hip/hip_bf16.h>
#include <math.h>

#define N_NODES 100000
#define N_EDGES 3200000
#define F0 489
#define KPAD 512
#define BSHIFT2 7                 // 128-node buckets
#define NBUCK2 782                // ceil(100000/128)
#define BW_CHUNK 16384
#define SRC_MASK 0x1FFFF          // 17 bits for src (< 131072)

typedef __attribute__((ext_vector_type(8))) short short8;
typedef __attribute__((ext_vector_type(4))) float f32x4;
typedef unsigned short ushort_t;
typedef unsigned int uint_t;

__device__ __forceinline__ short f2bf(float v) {
    return __builtin_bit_cast(short, __float2bfloat16(v));
}
// bf16 pair in a dword -> two floats
__device__ __forceinline__ float pair_lo(uint_t v) {
    union { uint_t i; float f; } c; c.i = v << 16; return c.f;
}
__device__ __forceinline__ float pair_hi(uint_t v) {
    union { uint_t i; float f; } c; c.i = v & 0xffff0000u; return c.f;
}
__device__ __forceinline__ void add8(float* acc, uint4 d) {
    acc[0] += pair_lo(d.x); acc[1] += pair_hi(d.x);
    acc[2] += pair_lo(d.y); acc[3] += pair_hi(d.y);
    acc[4] += pair_lo(d.z); acc[5] += pair_hi(d.z);
    acc[6] += pair_lo(d.w); acc[7] += pair_hi(d.w);
}

// ---------------- zero int buffer ----------------
__global__ void k_zero(int* a, int n) {
    int i = blockIdx.x * blockDim.x + threadIdx.x;
    if (i < n) a[i] = 0;
}

// ---------------- bucket histogram (LDS-aggregated) ----------------
__global__ __launch_bounds__(256) void k_bcount(const int* __restrict__ dst,
                                                int* __restrict__ bcnt) {
    __shared__ int lc[NBUCK2];
    for (int b = threadIdx.x; b < NBUCK2; b += 256) lc[b] = 0;
    __syncthreads();
    for (int e = blockIdx.x * 256 + threadIdx.x; e < N_EDGES; e += gridDim.x * 256)
        atomicAdd(&lc[dst[e] >> BSHIFT2], 1);
    __syncthreads();
    for (int b = threadIdx.x; b < NBUCK2; b += 256)
        if (lc[b] > 0) atomicAdd(&bcnt[b], lc[b]);
}

// ---------------- 1024-wide scan of bucket counts -> bbase (exclusive) ----------------
__global__ __launch_bounds__(1024) void k_bscan(const int* __restrict__ bcnt,
                                                int* __restrict__ bbase) {
    __shared__ int tmp[1024];
    int i = threadIdx.x;
    int v = (i < NBUCK2) ? bcnt[i] : 0;
    tmp[i] = v;
    __syncthreads();
    for (int off = 1; off < 1024; off <<= 1) {
        int t = (i >= off) ? tmp[i - off] : 0;
        __syncthreads();
        tmp[i] += t;
        __syncthreads();
    }
    bbase[i] = tmp[i] - v;          // exclusive
    if (i == 1023) bbase[1024] = tmp[i];
}

// ---------------- bin edges into bucket-contiguous packed u32 stream ----------------
__global__ __launch_bounds__(256) void k_binwrite(const int* __restrict__ src,
                                                  const int* __restrict__ dst,
                                                  const int* __restrict__ bbase,
                                                  int* __restrict__ bcur,
                                                  uint_t* __restrict__ binned) {
    __shared__ int lcnt[NBUCK2];
    __shared__ int lpos[NBUCK2];
    for (int b = threadIdx.x; b < NBUCK2; b += 256) lcnt[b] = 0;
    __syncthreads();
    int e0 = blockIdx.x * BW_CHUNK;
    int e1 = e0 + BW_CHUNK; if (e1 > N_EDGES) e1 = N_EDGES;
    for (int e = e0 + threadIdx.x; e < e1; e += 256)
        atomicAdd(&lcnt[dst[e] >> BSHIFT2], 1);
    __syncthreads();
    for (int b = threadIdx.x; b < NBUCK2; b += 256) {
        int c = lcnt[b];
        lpos[b] = (c > 0) ? (bbase[b] + atomicAdd(&bcur[b], c)) : 0;
    }
    __syncthreads();
    for (int e = e0 + threadIdx.x; e < e1; e += 256) {
        int d = dst[e];
        int b = d >> BSHIFT2;
        int pos = atomicAdd(&lpos[b], 1);
        binned[pos] = (uint_t)src[e] | ((uint_t)(d & 127) << 17);
    }
}

// ---------------- per-bucket CSR build (one L2 window); emits rowptr, dinv ----------------
__global__ __launch_bounds__(256) void k_fill3(const int* __restrict__ bbase,
                                               const uint_t* __restrict__ binned,
                                               int* __restrict__ rowptr,
                                               float* __restrict__ dinv,
                                               int* __restrict__ csr) {
    __shared__ int cnt[128];
    __shared__ int tmp[128];
    __shared__ int pos[128];
    int b = blockIdx.x;
    int node0 = b << BSHIFT2;
    int lo = bbase[b], hi = bbase[b + 1];
    int t = threadIdx.x;
    if (t < 128) cnt[t] = 0;
    __syncthreads();
    for (int i = lo + t; i < hi; i += 256)
        atomicAdd(&cnt[binned[i] >> 17], 1);
    __syncthreads();
    if (t < 128) tmp[t] = cnt[t];
    __syncthreads();
    for (int o = 1; o < 128; o <<= 1) {
        int v = 0;
        if (t < 128 && t >= o) v = tmp[t - o];
        __syncthreads();
        if (t < 128) tmp[t] += v;
        __syncthreads();
    }
    if (t < 128) {
        int excl = tmp[t] - cnt[t];
        pos[t] = excl;
        int node = node0 + t;
        if (node < N_NODES) {
            rowptr[node] = lo + excl;
            dinv[node] = rsqrtf((float)cnt[t] + 1.0f);
        } else if (node == N_NODES) {
            rowptr[node] = lo + excl;
        }
    }
    __syncthreads();
    for (int i = lo + t; i < hi; i += 256) {
        uint_t v = binned[i];
        int dloc = v >> 17;
        int p = atomicAdd(&pos[dloc], 1);
        csr[lo + p] = (int)(v & SRC_MASK);
    }
}

// ---------------- W1 -> bf16, transposed+padded: Wt[n][k], n<64, k<512 ----------------
__global__ void k_cvtW(const float* __restrict__ W1, short* __restrict__ Wt) {
    int i = blockIdx.x * 256 + threadIdx.x;
    if (i < 64 * KPAD) {
        int n = i >> 9, k = i & (KPAD - 1);
        float v = (k < F0) ? W1[k * 64 + n] : 0.f;
        Wt[i] = f2bf(v);
    }
}

// ---------------- layer 1 MFMA GEMM (R4 proven): LDS-staged via global_load_lds ----------------
__global__ __launch_bounds__(256) void k_gemm1_mfma(const float* __restrict__ x,
                                                    const short* __restrict__ Wt,
                                                    const float* __restrict__ dinv,
                                                    ushort_t* __restrict__ g1) {
    __shared__ float xs[64][68];         // 17.4 KB; +4 pad -> 2-way LDS conflict (free)
    int wave = threadIdx.x >> 6;
    int lane = threadIdx.x & 63;
    int quad = lane >> 4;
    int m = lane & 15;
    int row0 = blockIdx.x * 64;
    int wrow0 = wave * 16;

    f32x4 acc0 = {0.f, 0.f, 0.f, 0.f};
    f32x4 acc1 = {0.f, 0.f, 0.f, 0.f};
    f32x4 acc2 = {0.f, 0.f, 0.f, 0.f};
    f32x4 acc3 = {0.f, 0.f, 0.f, 0.f};

    const short* wb = Wt + m * KPAD + quad * 8;   // col-block 0 base
    const size_t XMAX = (size_t)N_NODES * F0 - 1;

    for (int chunk = 0; chunk < 8; ++chunk) {
        int kc = chunk * 64;
        __syncthreads();                 // previous chunk fully consumed
#pragma unroll
        for (int i = 0; i < 16; ++i) {
            int grow = row0 + wrow0 + i;
            int rowc = grow < N_NODES ? grow : N_NODES - 1;
            size_t gidx = (size_t)rowc * F0 + kc + lane;
            if (chunk == 7 && gidx > XMAX) gidx = XMAX;   // tail-of-row clamp
            __builtin_amdgcn_global_load_lds(
                (const __attribute__((address_space(1))) uint_t*)(x + gidx),
                (__attribute__((address_space(3))) uint_t*)&xs[wrow0 + i][0],
                4, 0, 0);
        }
        __syncthreads();                 // staging drained

        const float* lrow = &xs[wrow0 + m][0];
        if (chunk < 7) {
#pragma unroll
            for (int ksl = 0; ksl < 2; ++ksl) {
                const float* lr = lrow + ksl * 32 + quad * 8;
                f32x4 a0 = *(const f32x4*)(lr);
                f32x4 a1 = *(const f32x4*)(lr + 4);
                short8 af;
#pragma unroll
                for (int j = 0; j < 4; ++j) { af[j] = f2bf(a0[j]); af[4 + j] = f2bf(a1[j]); }
                const short* wk = wb + (chunk * 2 + ksl) * 32;
                short8 b0 = *(const short8*)(wk);
                short8 b1 = *(const short8*)(wk + 16 * KPAD);
                short8 b2 = *(const short8*)(wk + 32 * KPAD);
                short8 b3 = *(const short8*)(wk + 48 * KPAD);
                acc0 = __builtin_amdgcn_mfma_f32_16x16x32_bf16(af, b0, acc0, 0, 0, 0);
                acc1 = __builtin_amdgcn_mfma_f32_16x16x32_bf16(af, b1, acc1, 0, 0, 0);
                acc2 = __builtin_amdgcn_mfma_f32_16x16x32_bf16(af, b2, acc2, 0, 0, 0);
                acc3 = __builtin_amdgcn_mfma_f32_16x16x32_bf16(af, b3, acc3, 0, 0, 0);
            }
        } else {
            {   // ks_global = 14, k = 448..479, all valid
                const float* lr = lrow + quad * 8;
                f32x4 a0 = *(const f32x4*)(lr);
                f32x4 a1 = *(const f32x4*)(lr + 4);
                short8 af;
#pragma unroll
                for (int j = 0; j < 4; ++j) { af[j] = f2bf(a0[j]); af[4 + j] = f2bf(a1[j]); }
                const short* wk = wb + 14 * 32;
                short8 b0 = *(const short8*)(wk);
                short8 b1 = *(const short8*)(wk + 16 * KPAD);
                short8 b2 = *(const short8*)(wk + 32 * KPAD);
                short8 b3 = *(const short8*)(wk + 48 * KPAD);
                acc0 = __builtin_amdgcn_mfma_f32_16x16x32_bf16(af, b0, acc0, 0, 0, 0);
                acc1 = __builtin_amdgcn_mfma_f32_16x16x32_bf16(af, b1, acc1, 0, 0, 0);
                acc2 = __builtin_amdgcn_mfma_f32_16x16x32_bf16(af, b2, acc2, 0, 0, 0);
                acc3 = __builtin_amdgcn_mfma_f32_16x16x32_bf16(af, b3, acc3, 0, 0, 0);
            }
            {   // ks_global = 15, k = 480..511, valid only k < 489
                int kb = 480 + quad * 8;
                const float* lr = lrow + 32 + quad * 8;
                short8 af;
#pragma unroll
                for (int j = 0; j < 8; ++j)
                    af[j] = (kb + j < F0) ? f2bf(lr[j]) : (short)0;
                const short* wk = wb + 15 * 32;
                short8 b0 = *(const short8*)(wk);
                short8 b1 = *(const short8*)(wk + 16 * KPAD);
                short8 b2 = *(const short8*)(wk + 32 * KPAD);
                short8 b3 = *(const short8*)(wk + 48 * KPAD);
                acc0 = __builtin_amdgcn_mfma_f32_16x16x32_bf16(af, b0, acc0, 0, 0, 0);
                acc1 = __builtin_amdgcn_mfma_f32_16x16x32_bf16(af, b1, acc1, 0, 0, 0);
                acc2 = __builtin_amdgcn_mfma_f32_16x16x32_bf16(af, b2, acc2, 0, 0, 0);
                acc3 = __builtin_amdgcn_mfma_f32_16x16x32_bf16(af, b3, acc3, 0, 0, 0);
            }
        }
    }

    // ---- epilogue: D layout col = lane&15, row = quad*4 + reg ----
#pragma unroll
    for (int r = 0; r < 4; r++) {
        int orow = row0 + wrow0 + quad * 4 + r;
        if (orow < N_NODES) {
            float s = dinv[orow];
            ushort_t* gr = g1 + (size_t)orow * 64 + m;
            gr[0]  = (ushort_t)f2bf(s * acc0[r]);
            gr[16] = (ushort_t)f2bf(s * acc1[r]);
            gr[32] = (ushort_t)f2bf(s * acc2[r]);
            gr[48] = (ushort_t)f2bf(s * acc3[r]);
        }
    }
}

// ---------------- gather64 v4: 2 nodes/wave, issue-all-8-loads-first ----------------
// 32 lanes/node: slot = l2&7 (uint4 of row), group = l2>>3 (0..3); chunk = 32 edges;
// lane's edges e_j = grp + 4j (j=0..7) -> 8 independent dwordx4 loads in flight.
__global__ __launch_bounds__(256) void k_gather64(const int* __restrict__ rowptr,
                                                  const int* __restrict__ csr,
                                                  const uint_t* __restrict__ g,
                                                  float* __restrict__ agg) {
    int node = blockIdx.x * 8 + (threadIdx.x >> 5);
    int lane = threadIdx.x & 63;
    int l2 = lane & 31;
    int slot = l2 & 7;
    int grp = l2 >> 3;               // 0..3
    int base32 = lane & 32;          // shfl base for this half-wave
    int beg = rowptr[node], end = rowptr[node + 1];
    const uint4* g4 = reinterpret_cast<const uint4*>(g);   // row = 8 uint4
    float acc[8] = {0.f, 0.f, 0.f, 0.f, 0.f, 0.f, 0.f, 0.f};
    if (grp == 0) add8(acc, g4[(size_t)node * 8 + slot]);  // self loop
    for (int j0 = beg; j0 < end; j0 += 32) {
        int n = end - j0;
        if (n > 32) n = 32;
        int ev = csr[j0 + (l2 < n ? l2 : n - 1)];
        int sj[8];
#pragma unroll
        for (int j = 0; j < 8; ++j) {
            int ej = grp + 4 * j;
            sj[j] = __shfl(ev, base32 + (ej < n ? ej : 0), 64);
        }
        uint4 d[8];
#pragma unroll
        for (int j = 0; j < 8; ++j) d[j] = g4[(size_t)sj[j] * 8 + slot];
#pragma unroll
        for (int j = 0; j < 8; ++j) if (grp + 4 * j < n) add8(acc, d[j]);
    }
    // reduce across the 4 groups (bits 3..4 of l2; stays within half-wave)
#pragma unroll
    for (int off = 8; off < 32; off <<= 1) {
#pragma unroll
        for (int k = 0; k < 8; k++) acc[k] += __shfl_xor(acc[k], off, 64);
    }
    if (grp == 0) {
        float4* ap = reinterpret_cast<float4*>(agg + (size_t)node * 64 + slot * 8);
        ap[0] = make_float4(acc[0], acc[1], acc[2], acc[3]);
        ap[1] = make_float4(acc[4], acc[5], acc[6], acc[7]);
    }
}

// ---------------- gather32 v4: 2 nodes/wave, issue-all-4-loads-first ----------------
// 32 lanes/node: slot = l2&3, group = l2>>2 (0..7); chunk = 32 edges;
// lane's edges e_j = grp + 8j (j=0..3) -> 4 independent dwordx4 loads in flight.
__global__ __launch_bounds__(256) void k_gather32(const int* __restrict__ rowptr,
                                                  const int* __restrict__ csr,
                                                  const uint_t* __restrict__ g,
                                                  float* __restrict__ agg) {
    int node = blockIdx.x * 8 + (threadIdx.x >> 5);
    int lane = threadIdx.x & 63;
    int l2 = lane & 31;
    int slot = l2 & 3;
    int grp = l2 >> 2;               // 0..7
    int base32 = lane & 32;
    int beg = rowptr[node], end = rowptr[node + 1];
    const uint4* g4 = reinterpret_cast<const uint4*>(g);   // row = 4 uint4
    float acc[8] = {0.f, 0.f, 0.f, 0.f, 0.f, 0.f, 0.f, 0.f};
    if (grp == 0) add8(acc, g4[(size_t)node * 4 + slot]);  // self loop
    for (int j0 = beg; j0 < end; j0 += 32) {
        int n = end - j0;
        if (n > 32) n = 32;
        int ev = csr[j0 + (l2 < n ? l2 : n - 1)];
        int sj[4];
#pragma unroll
        for (int j = 0; j < 4; ++j) {
            int ej = grp + 8 * j;
            sj[j] = __shfl(ev, base32 + (ej < n ? ej : 0), 64);
        }
        uint4 d[4];
#pragma unroll
        for (int j = 0; j < 4; ++j) d[j] = g4[(size_t)sj[j] * 4 + slot];
#pragma unroll
        for (int j = 0; j < 4; ++j) if (grp + 8 * j < n) add8(acc, d[j]);
    }
    // reduce across the 8 groups (bits 2..4 of l2; stays within half-wave)
#pragma unroll
    for (int off = 4; off < 32; off <<= 1) {
#pragma unroll
        for (int k = 0; k < 8; k++) acc[k] += __shfl_xor(acc[k], off, 64);
    }
    if (grp == 0) {
        float4* ap = reinterpret_cast<float4*>(agg + (size_t)node * 32 + slot * 8);
        ap[0] = make_float4(acc[0], acc[1], acc[2], acc[3]);
        ap[1] = make_float4(acc[4], acc[5], acc[6], acc[7]);
    }
}

// ---------------- gather2 v3: 16 lanes per node ----------------
__global__ __launch_bounds__(256) void k_gather2(const int* __restrict__ rowptr,
                                                 const int* __restrict__ csr,
                                                 const float* __restrict__ g,
                                                 float* __restrict__ agg) {
    int node = blockIdx.x * 16 + (threadIdx.x >> 4);
    int l16 = threadIdx.x & 15;
    int beg = rowptr[node], end = rowptr[node + 1];
    const float2* gp = reinterpret_cast<const float2*>(g);
    float ax = 0.f, ay = 0.f;
    if (l16 == 0) {
        float2 sv = gp[node];
        ax = sv.x; ay = sv.y;
    }
    for (int j = beg + l16; j < end; j += 16) {
        float2 v = gp[csr[j]];
        ax += v.x;
        ay += v.y;
    }
#pragma unroll
    for (int off = 1; off < 16; off <<= 1) {
        ax += __shfl_xor(ax, off, 64);
        ay += __shfl_xor(ay, off, 64);
    }
    if (l16 == 0) {
        reinterpret_cast<float2*>(agg)[node] = make_float2(ax, ay);
    }
}

// ---------------- layer 2: g2 = bf16( dinv .* (relu(dinv*agg1+b1) @ W2) ) ----------------
__global__ __launch_bounds__(256) void k_layer2(const float* __restrict__ agg1,
                                                const float* __restrict__ dinv,
                                                const float* __restrict__ b1,
                                                const float* __restrict__ W2,
                                                ushort_t* __restrict__ g2) {
    __shared__ float hs[32][65];
    __shared__ float Ws[64 * 32];
    for (int i = threadIdx.x; i < 64 * 32; i += 256) Ws[i] = W2[i];
    int row0 = blockIdx.x * 32;
    for (int i = threadIdx.x; i < 32 * 64; i += 256) {
        int r = i >> 6, f = i & 63;
        int row = row0 + r;
        float v = dinv[row] * agg1[(size_t)row * 64 + f] + b1[f];
        hs[r][f] = fmaxf(v, 0.f);
    }
    __syncthreads();
    int r = threadIdx.x >> 3;
    int j0 = (threadIdx.x & 7) * 4;
    int row = row0 + r;
    float a0 = 0.f, a1 = 0.f, a2 = 0.f, a3 = 0.f;
#pragma unroll 8
    for (int f = 0; f < 64; f++) {
        float h = hs[r][f];
        a0 += h * Ws[f * 32 + j0 + 0];
        a1 += h * Ws[f * 32 + j0 + 1];
        a2 += h * Ws[f * 32 + j0 + 2];
        a3 += h * Ws[f * 32 + j0 + 3];
    }
    float s = dinv[row];
    ushort_t* gr = g2 + (size_t)row * 32 + j0;
    gr[0] = (ushort_t)f2bf(s * a0);
    gr[1] = (ushort_t)f2bf(s * a1);
    gr[2] = (ushort_t)f2bf(s * a2);
    gr[3] = (ushort_t)f2bf(s * a3);
}

// ---------------- layer 3 ----------------
__global__ __launch_bounds__(256) void k_layer3(const float* __restrict__ agg2,
                                                const float* __restrict__ dinv,
                                                const float* __restrict__ b2,
                                                const float* __restrict__ W3,
                                                float* __restrict__ g3) {
    int row = blockIdx.x * blockDim.x + threadIdx.x;
    if (row >= N_NODES) return;
    float s = dinv[row];
    float t0 = 0.f, t1 = 0.f;
    const float4* ar = reinterpret_cast<const float4*>(agg2 + (size_t)row * 32);
#pragma unroll
    for (int q = 0; q < 8; q++) {
        float4 v = ar[q];
        float h;
        int f = q * 4;
        h = fmaxf(s * v.x + b2[f + 0], 0.f); t0 += h * W3[(f + 0) * 2]; t1 += h * W3[(f + 0) * 2 + 1];
        h = fmaxf(s * v.y + b2[f + 1], 0.f); t0 += h * W3[(f + 1) * 2]; t1 += h * W3[(f + 1) * 2 + 1];
        h = fmaxf(s * v.z + b2[f + 2], 0.f); t0 += h * W3[(f + 2) * 2]; t1 += h * W3[(f + 2) * 2 + 1];
        h = fmaxf(s * v.w + b2[f + 3], 0.f); t0 += h * W3[(f + 3) * 2]; t1 += h * W3[(f + 3) * 2 + 1];
    }
    float2 o = make_float2(s * t0, s * t1);
    *reinterpret_cast<float2*>(g3 + (size_t)row * 2) = o;
}

// ---------------- final log_softmax ----------------
__global__ void k_final(const float* __restrict__ agg3,
                        const float* __restrict__ dinv,
                        const float* __restrict__ b3,
                        float* __restrict__ out) {
    int row = blockIdx.x * blockDim.x + threadIdx.x;
    if (row >= N_NODES) return;
    float s = dinv[row];
    float2 a = *reinterpret_cast<const float2*>(agg3 + (size_t)row * 2);
    float z0 = s * a.x + b3[0];
    float z1 = s * a.y + b3[1];
    float m = fmaxf(z0, z1);
    float lse = m + logf(expf(z0 - m) + expf(z1 - m));
    out[(size_t)row * 2 + 0] = z0 - lse;
    out[(size_t)row * 2 + 1] = z1 - lse;
}

extern "C" void kernel_launch(void* const* d_in, const int* in_sizes, int n_in,
                              void* d_out, int out_size, void* d_ws, size_t ws_size,
                              hipStream_t stream) {
    const float* x  = (const float*)d_in[0];
    const int*   ei = (const int*)d_in[1];
    const float* W1 = (const float*)d_in[2];
    const float* b1 = (const float*)d_in[3];
    const float* W2 = (const float*)d_in[4];
    const float* b2 = (const float*)d_in[5];
    const float* W3 = (const float*)d_in[6];
    const float* b3 = (const float*)d_in[7];
    float* out = (float*)d_out;

    const int* src = ei;
    const int* dst = ei + N_EDGES;

    // ---- workspace layout (int elements) ----
    int* bcnt   = (int*)d_ws;                    // 1024
    int* bcur   = bcnt + 1024;                   // 1024  (zero bcnt+bcur = 2048)
    int* bbase  = bcur + 1024;                   // 1028
    int* rowptr = bbase + 1028;                  // 100004
    int* csr    = rowptr + 100004;               // 3200000
    float* dinv = (float*)(csr + 3200000);       // 100000
    short* Wt   = (short*)(dinv + 100000);       // 32768 shorts = 16384 ints
    uint_t* binned = (uint_t*)((int*)Wt + 16384);         // 3.2M u32 = 12.8 MB
    ushort_t* gbuf = (ushort_t*)(binned + N_EDGES);       // N*64 ushort = 12.8 MB
    float* aggF = (float*)(gbuf + (size_t)N_NODES * 64);  // N*64 fp32 = 25.6 MB

    ushort_t* gb1 = gbuf;
    ushort_t* gb2 = gbuf;
    float* g3     = (float*)gbuf;   // gb2 dead after gather32
    float* agg1 = aggF;
    float* agg2 = aggF;
    float* agg3 = aggF;

    const int TB = 256;
    int nb_nodes = (N_NODES + TB - 1) / TB;      // 391
    int nb_bw    = (N_EDGES + BW_CHUNK - 1) / BW_CHUNK;  // 196

    k_zero<<<8, TB, 0, stream>>>(bcnt, 2048);
    k_bcount<<<2048, TB, 0, stream>>>(dst, bcnt);
    k_bscan<<<1, 1024, 0, stream>>>(bcnt, bbase);
    k_binwrite<<<nb_bw, TB, 0, stream>>>(src, dst, bbase, bcur, binned);
    k_fill3<<<NBUCK2, TB, 0, stream>>>(bbase, binned, rowptr, dinv, csr);
    k_cvtW<<<(64 * KPAD + 255) / 256, 256, 0, stream>>>(W1, Wt);

    k_gemm1_mfma<<<(N_NODES + 63) / 64, TB, 0, stream>>>(x, Wt, dinv, gb1);
    k_gather64<<<N_NODES / 8, TB, 0, stream>>>(rowptr, csr, (const uint_t*)gb1, agg1);

    k_layer2<<<N_NODES / 32, TB, 0, stream>>>(agg1, dinv, b1, W2, gb2);
    k_gather32<<<N_NODES / 8, TB, 0, stream>>>(rowptr, csr, (const uint_t*)gb2, agg2);

    k_layer3<<<nb_nodes, TB, 0, stream>>>(agg2, dinv, b2, W3, g3);
    k_gather2<<<N_NODES / 16, TB, 0, stream>>>(rowptr, csr, g3, agg3);

    k_final<<<nb_nodes, TB, 0, stream>>>(agg3, dinv, b3, out);
}